// Round 1
// baseline (695.796 us; speedup 1.0000x reference)
//
#include <hip/hip_runtime.h>
#include <math.h>

// ---------------- workspace layout (bytes) ----------------
#define OFF_SIMKEY   0          // u64[8]
#define OFF_POOLED   1024       // f32[8*512]
#define ZEROED_BYTES 17408
#define OFF_MAXSIM   17408      // f32[8]
#define OFF_NORME    17664      // f32[8]
#define OFF_EBEST    17920      // f32[8*512]
#define OFF_BPRIME   34304      // f32[512]
#define OFF_WP       36864      // bf16[512*512]  (W' = W1 @ Wc)
#define OFF_W2B      561152     // bf16[512*512]

typedef __attribute__((ext_vector_type(8))) short bf16x8;
typedef __attribute__((ext_vector_type(4))) float f32x4;

__device__ inline unsigned short f2bf(float f) {
    unsigned int u = __float_as_uint(f);
    unsigned int r = (u + 0x7FFFu + ((u >> 16) & 1u)) >> 16;
    return (unsigned short)r;
}

// ---------------- W' = W1 @ Wc (bf16), b' = b1 + W1 @ bc ----------------
__global__ void __launch_bounds__(256) k_pre(const float* __restrict__ W1, const float* __restrict__ Wc,
                      const float* __restrict__ b1, const float* __restrict__ bc,
                      unsigned short* __restrict__ Wp, float* __restrict__ bprime) {
    __shared__ float w1row[512];
    __shared__ float wsum[4];
    int t = threadIdx.x;
    int n = blockIdx.x >> 1, half = blockIdx.x & 1;
    if (t < 128) ((float4*)w1row)[t] = ((const float4*)(W1 + (size_t)n * 512))[t];
    __syncthreads();
    int k = half * 256 + t;
    float acc = 0.f;
#pragma unroll 8
    for (int j = 0; j < 512; ++j) acc += w1row[j] * Wc[(size_t)j * 512 + k];
    Wp[(size_t)n * 512 + k] = f2bf(acc);
    if (half == 0) {
        float p = w1row[t] * bc[t] + w1row[t + 256] * bc[t + 256];
#pragma unroll
        for (int m = 32; m >= 1; m >>= 1) p += __shfl_xor(p, m);
        if ((t & 63) == 0) wsum[t >> 6] = p;
        __syncthreads();
        if (t == 0) bprime[n] = b1[n] + wsum[0] + wsum[1] + wsum[2] + wsum[3];
    }
}

// ---------------- W2 -> bf16 ----------------
__global__ void __launch_bounds__(256) k_cast(const float* __restrict__ W2, unsigned short* __restrict__ W2b) {
    int i = blockIdx.x * 1024 + threadIdx.x * 4;
    float4 v = *(const float4*)(W2 + i);
    ushort4 o;
    o.x = f2bf(v.x); o.y = f2bf(v.y); o.z = f2bf(v.z); o.w = f2bf(v.w);
    *(ushort4*)(W2b + i) = o;
}

// ---------------- pooled sum over L (float4 loads, LDS pre-reduce) ----------------
__global__ void __launch_bounds__(512) k_pool(const float* __restrict__ x, float* __restrict__ pooled) {
    __shared__ float4 pb[4][128];
    int t = threadIdx.x;
    int q = t & 127;
    int rg = t >> 7;
    int b = blockIdx.y;
    int l0 = blockIdx.x * 128;
    const float4* p = (const float4*)(x + ((size_t)b * 8192 + l0 + rg) * 512) + q;
    float4 s = make_float4(0.f, 0.f, 0.f, 0.f);
#pragma unroll 8
    for (int i = 0; i < 32; ++i) {
        float4 v = p[(size_t)i * 512];
        s.x += v.x; s.y += v.y; s.z += v.z; s.w += v.w;
    }
    pb[rg][q] = s;
    __syncthreads();
    if (rg == 0) {
        float4 a = pb[0][q], b1_ = pb[1][q], c = pb[2][q], d = pb[3][q];
        atomicAdd(&pooled[b * 512 + q * 4 + 0], a.x + b1_.x + c.x + d.x);
        atomicAdd(&pooled[b * 512 + q * 4 + 1], a.y + b1_.y + c.y + d.y);
        atomicAdd(&pooled[b * 512 + q * 4 + 2], a.z + b1_.z + c.z + d.z);
        atomicAdd(&pooled[b * 512 + q * 4 + 3], a.w + b1_.w + c.w + d.w);
    }
}

// ---------------- sim scan: argmax cos(pooled_b, E_s) over active s ----------------
__global__ void __launch_bounds__(256) k_sim(const float* __restrict__ E, const float* __restrict__ sl,
                     const float* __restrict__ pooledws, unsigned long long* __restrict__ simkey) {
    __shared__ float ps[4096];
    __shared__ unsigned long long wkey[4][8];
    int t = threadIdx.x, lane = t & 63, w = t >> 6;
#pragma unroll
    for (int c = 0; c < 16; ++c) ps[t + c * 256] = pooledws[t + c * 256] * (1.0f / 8192.0f);
    __syncthreads();
    float pr[8][8];
#pragma unroll
    for (int b = 0; b < 8; ++b) {
        float4 v0 = *(const float4*)&ps[b * 512 + lane * 8];
        float4 v1 = *(const float4*)&ps[b * 512 + lane * 8 + 4];
        pr[b][0] = v0.x; pr[b][1] = v0.y; pr[b][2] = v0.z; pr[b][3] = v0.w;
        pr[b][4] = v1.x; pr[b][5] = v1.y; pr[b][6] = v1.z; pr[b][7] = v1.w;
    }
    float npinv[8];
#pragma unroll
    for (int b = 0; b < 8; ++b) {
        float s = 0.f;
#pragma unroll
        for (int j = 0; j < 8; ++j) s += pr[b][j] * pr[b][j];
#pragma unroll
        for (int m = 32; m >= 1; m >>= 1) s += __shfl_xor(s, m);
        npinv[b] = 1.0f / fmaxf(sqrtf(s), 1e-8f);
    }
    unsigned long long best[8];
#pragma unroll
    for (int b = 0; b < 8; ++b) best[b] = 0ull;
    int sbase = blockIdx.x * 64 + w * 16;
    float mysl = (lane < 16) ? sl[sbase + lane] : 0.f;
    unsigned long long mask = __ballot(mysl > 0.0f);
    for (int it = 0; it < 16; ++it) {
        if (!((mask >> it) & 1ull)) continue;
        int s = sbase + it;
        const float4* ep = (const float4*)(E + (size_t)s * 512);
        float4 e0 = ep[lane * 2], e1 = ep[lane * 2 + 1];
        float nrm = e0.x * e0.x + e0.y * e0.y + e0.z * e0.z + e0.w * e0.w
                  + e1.x * e1.x + e1.y * e1.y + e1.z * e1.z + e1.w * e1.w;
        float dt[8];
#pragma unroll
        for (int b = 0; b < 8; ++b)
            dt[b] = e0.x * pr[b][0] + e0.y * pr[b][1] + e0.z * pr[b][2] + e0.w * pr[b][3]
                  + e1.x * pr[b][4] + e1.y * pr[b][5] + e1.z * pr[b][6] + e1.w * pr[b][7];
#pragma unroll
        for (int m = 32; m >= 1; m >>= 1) {
            nrm += __shfl_xor(nrm, m);
#pragma unroll
            for (int b = 0; b < 8; ++b) dt[b] += __shfl_xor(dt[b], m);
        }
        float neinv = 1.0f / fmaxf(sqrtf(nrm), 1e-8f);
#pragma unroll
        for (int b = 0; b < 8; ++b) {
            float sim = dt[b] * npinv[b] * neinv;
            unsigned int u = __float_as_uint(sim);
            unsigned int k32 = (u & 0x80000000u) ? ~u : (u | 0x80000000u);
            unsigned long long key = ((unsigned long long)k32 << 32) | (unsigned int)(~(unsigned int)s);
            if (key > best[b]) best[b] = key;
        }
    }
    if (lane == 0) {
#pragma unroll
        for (int b = 0; b < 8; ++b) wkey[w][b] = best[b];
    }
    __syncthreads();
    if (t < 8) {
        unsigned long long k = wkey[0][t];
#pragma unroll
        for (int w2 = 1; w2 < 4; ++w2) if (wkey[w2][t] > k) k = wkey[w2][t];
        if (k) atomicMax(&simkey[t], k);
    }
}

// ---------------- decode best, gather embedding + norm ----------------
__global__ void __launch_bounds__(64) k_b2(const float* __restrict__ E, const unsigned long long* __restrict__ simkey,
                    float* __restrict__ max_sim, float* __restrict__ norm_e, float* __restrict__ ebest) {
    int b = blockIdx.x, lane = threadIdx.x;
    unsigned long long key = simkey[b];
    float ms; unsigned int idx;
    if (key == 0ull) { ms = -1e30f; idx = 0u; }
    else {
        unsigned int k32 = (unsigned int)(key >> 32);
        unsigned int u = (k32 & 0x80000000u) ? (k32 & 0x7FFFFFFFu) : ~k32;
        ms = __uint_as_float(u);
        idx = ~(unsigned int)(key & 0xFFFFFFFFull);
    }
    const float4* ep = (const float4*)(E + (size_t)idx * 512);
    float4 e0 = ep[lane * 2], e1 = ep[lane * 2 + 1];
    *(float4*)&ebest[b * 512 + lane * 8] = e0;
    *(float4*)&ebest[b * 512 + lane * 8 + 4] = e1;
    float s = e0.x * e0.x + e0.y * e0.y + e0.z * e0.z + e0.w * e0.w
            + e1.x * e1.x + e1.y * e1.y + e1.z * e1.z + e1.w * e1.w;
#pragma unroll
    for (int m = 32; m >= 1; m >>= 1) s += __shfl_xor(s, m);
    if (lane == 0) { max_sim[b] = ms; norm_e[b] = fmaxf(sqrtf(s), 1e-8f); }
}

// ---------------- mega v3: barrier-free K-loops, B-frags direct from L2 ----------------
// Insight: each staged B byte was consumed by exactly ONE wave (waves own disjoint
// 64-col slabs) -> LDS staging of B was pure overhead. B fragments now load straight
// from L2-resident Wp/W2b (16 rows x 64B contiguous per wave). Freed LDS holds ALL
// 16 A k-chunks (Ts-full, staged once in prologue). A keeps its 8x LDS broadcast.
// Result: 3 barriers total (vs 33), no vmcnt(0) drains, fully unrolled K-loops.
// LDS: Ts 64K @0 | Hs 64K @65536 | red 6K @131072 = 137216.
__global__ void __launch_bounds__(512, 2) k_mega(
        const float* __restrict__ x, const unsigned short* __restrict__ Wp,
        const float* __restrict__ bprime, const unsigned short* __restrict__ W2b,
        const float* __restrict__ b2, const float* __restrict__ ebest,
        const float* __restrict__ max_sim, const float* __restrict__ norm_e,
        float* __restrict__ out) {
    __shared__ char smem[137216];
    unsigned int*   Ts32 = (unsigned int*)(smem);
    unsigned short* Ts   = (unsigned short*)(smem);
    unsigned short* Hs   = (unsigned short*)(smem + 65536);
    float*          red  = (float*)(smem + 131072);

    const int t = threadIdx.x;
    const int lane = t & 63, w = t >> 6;
    const int l15 = lane & 15, quad = lane >> 4;
    const int gr0 = blockIdx.x * 64;
    const int b = gr0 >> 13;

    // ---- A staging geometry: thread owns row r, dword pair {cc, cc+8} per kt ----
    const int r = t >> 3, cc = t & 7;
    const int sR = (r >> 1) & 3;
    const int d0 = (((cc >> 2) ^ sR) << 2) | (cc & 3);
    const int d1 = ((((cc >> 2) + 2) ^ sR) << 2) | (cc & 3);

    // fragment read offsets (ushort units, swizzled)
    int tsoff[4], hoff[4];
#pragma unroll
    for (int i = 0; i < 4; ++i) {
        int rowA = i * 16 + l15;
        tsoff[i] = rowA * 32 + ((quad ^ ((rowA >> 1) & 3)) << 3);
        hoff[i]  = rowA * 32 + ((quad ^ ((rowA >> 2) & 3)) << 3);
    }

    // B fragment pointers: direct global (L2-hit), dwordx4 per frag, kt*32 folds to imm offset
    const unsigned short* bp1[4];
    const unsigned short* bp2[4];
#pragma unroll
    for (int j = 0; j < 4; ++j) {
        int n = w * 64 + j * 16 + l15;
        bp1[j] = Wp  + n * 512 + quad * 8;
        bp2[j] = W2b + n * 512 + quad * 8;
    }

    // ---- prologue: stage ALL 16 A k-chunks into Ts (bf16, swizzled) ----
    {
        int gr = gr0 + r;
        bool z = ((gr & 8191) == 0);
        const float* src = x + ((size_t)gr - 1) * 512 + cc * 2;
#pragma unroll
        for (int kt = 0; kt < 16; ++kt) {
            float2 v0 = make_float2(0.f, 0.f), v1 = make_float2(0.f, 0.f);
            if (!z) { v0 = *(const float2*)(src + kt * 32); v1 = *(const float2*)(src + kt * 32 + 16); }
            Ts32[kt * 1024 + r * 16 + d0] = (unsigned int)f2bf(v0.x) | ((unsigned int)f2bf(v0.y) << 16);
            Ts32[kt * 1024 + r * 16 + d1] = (unsigned int)f2bf(v1.x) | ((unsigned int)f2bf(v1.y) << 16);
        }
    }
    __syncthreads();

    // ================= GEMM1 K-loop (barrier-free) =================
    f32x4 acc[4][4];
#pragma unroll
    for (int i = 0; i < 4; ++i)
#pragma unroll
        for (int j = 0; j < 4; ++j) acc[i][j] = (f32x4){0.f, 0.f, 0.f, 0.f};
#pragma unroll
    for (int kt = 0; kt < 16; ++kt) {
        bf16x8 af[4], bfr[4];
#pragma unroll
        for (int i = 0; i < 4; ++i) af[i] = *(const bf16x8*)&Ts[kt * 2048 + tsoff[i]];
#pragma unroll
        for (int j = 0; j < 4; ++j) bfr[j] = *(const bf16x8*)(bp1[j] + kt * 32);
#pragma unroll
        for (int i = 0; i < 4; ++i)
#pragma unroll
            for (int j = 0; j < 4; ++j)
                acc[i][j] = __builtin_amdgcn_mfma_f32_16x16x32_bf16(af[i], bfr[j], acc[i][j], 0, 0, 0);
    }

    // ---- GEMM1 epilogue: bias + exact gelu -> Hs (swizzled) ----
    {
        float bpj[4];
#pragma unroll
        for (int j = 0; j < 4; ++j) bpj[j] = bprime[w * 64 + j * 16 + l15];
#pragma unroll
        for (int i = 0; i < 4; ++i)
#pragma unroll
            for (int j = 0; j < 4; ++j)
#pragma unroll
                for (int rg = 0; rg < 4; ++rg) {
                    int m = i * 16 + quad * 4 + rg;
                    int ktc = w * 2 + (j >> 1);
                    int grp = ((j & 1) * 2 + (l15 >> 3)) ^ ((m >> 2) & 3);
                    float v = acc[i][j][rg] + bpj[j];
                    v = 0.5f * v * (1.0f + erff(v * 0.70710678118f));
                    Hs[ktc * 2048 + m * 32 + grp * 8 + (l15 & 7)] = f2bf(v);
                }
    }
    __syncthreads();

    // ================= GEMM2 K-loop (barrier-free) =================
    f32x4 acc2[4][4];
#pragma unroll
    for (int i = 0; i < 4; ++i)
#pragma unroll
        for (int j = 0; j < 4; ++j) acc2[i][j] = (f32x4){0.f, 0.f, 0.f, 0.f};
#pragma unroll
    for (int kt = 0; kt < 16; ++kt) {
        bf16x8 af[4], bfr[4];
#pragma unroll
        for (int i = 0; i < 4; ++i) af[i] = *(const bf16x8*)&Hs[kt * 2048 + hoff[i]];
#pragma unroll
        for (int j = 0; j < 4; ++j) bfr[j] = *(const bf16x8*)(bp2[j] + kt * 32);
#pragma unroll
        for (int i = 0; i < 4; ++i)
#pragma unroll
            for (int j = 0; j < 4; ++j)
                acc2[i][j] = __builtin_amdgcn_mfma_f32_16x16x32_bf16(af[i], bfr[j], acc2[i][j], 0, 0, 0);
    }

    // ---- GEMM2 epilogue: ssd/nx2/xdot partials, cross-wave reduce, out ----
    {
        float b2j[4], ej[4];
#pragma unroll
        for (int j = 0; j < 4; ++j) {
            int n = w * 64 + j * 16 + l15;
            b2j[j] = b2[n];
            ej[j] = ebest[b * 512 + n];
        }
#pragma unroll
        for (int i = 0; i < 4; ++i)
#pragma unroll
            for (int rg = 0; rg < 4; ++rg) {
                int m = i * 16 + quad * 4 + rg;
                int gr = gr0 + m;
                float sd = 0.f, sx = 0.f, sdt = 0.f;
#pragma unroll
                for (int j = 0; j < 4; ++j) {
                    int n = w * 64 + j * 16 + l15;
                    float p = acc2[i][j][rg] + b2j[j];
                    float xv = x[(size_t)gr * 512 + n];
                    float d = xv - p;
                    sd += d * d; sx += xv * xv; sdt += xv * ej[j];
                }
#pragma unroll
                for (int mm = 8; mm >= 1; mm >>= 1) {
                    sd += __shfl_xor(sd, mm);
                    sx += __shfl_xor(sx, mm);
                    sdt += __shfl_xor(sdt, mm);
                }
                if (l15 == 0) {
                    red[(m * 8 + w) * 3 + 0] = sd;
                    red[(m * 8 + w) * 3 + 1] = sx;
                    red[(m * 8 + w) * 3 + 2] = sdt;
                }
            }
    }
    __syncthreads();
    if (t < 64) {
        float sd = 0.f, sx = 0.f, sdt = 0.f;
#pragma unroll
        for (int w2 = 0; w2 < 8; ++w2) {
            sd  += red[(t * 8 + w2) * 3 + 0];
            sx  += red[(t * 8 + w2) * 3 + 1];
            sdt += red[(t * 8 + w2) * 3 + 2];
        }
        float ps = sqrtf(sd * (1.0f / 512.0f));
        float ms = max_sim[b];
        float c = 0.f;
        if (ms > 0.3f) {
            float nx = fmaxf(sqrtf(sx), 1e-8f);
            c = 2.0f * (1.0f - sdt / (nx * norm_e[b]));
        }
        out[gr0 + t] = fmaxf(ps, c);
    }
}

extern "C" void kernel_launch(void* const* d_in, const int* in_sizes, int n_in,
                              void* d_out, int out_size, void* d_ws, size_t ws_size,
                              hipStream_t stream) {
    const float* x  = (const float*)d_in[0];
    const float* Wc = (const float*)d_in[1];
    const float* bc = (const float*)d_in[2];
    const float* W1 = (const float*)d_in[3];
    const float* b1 = (const float*)d_in[4];
    const float* W2 = (const float*)d_in[5];
    const float* b2 = (const float*)d_in[6];
    const float* E  = (const float*)d_in[7];
    const float* sl = (const float*)d_in[8];

    char* ws = (char*)d_ws;
    unsigned long long* simkey = (unsigned long long*)(ws + OFF_SIMKEY);
    float* pooled  = (float*)(ws + OFF_POOLED);
    float* max_sim = (float*)(ws + OFF_MAXSIM);
    float* norm_e  = (float*)(ws + OFF_NORME);
    float* ebest   = (float*)(ws + OFF_EBEST);
    float* bprime  = (float*)(ws + OFF_BPRIME);
    unsigned short* Wp  = (unsigned short*)(ws + OFF_WP);
    unsigned short* W2b = (unsigned short*)(ws + OFF_W2B);
    float* out = (float*)d_out;

    hipMemsetAsync(ws, 0, ZEROED_BYTES, stream);
    k_pre<<<1024, 256, 0, stream>>>(W1, Wc, b1, bc, Wp, bprime);
    k_cast<<<256, 256, 0, stream>>>(W2, W2b);
    k_pool<<<dim3(64, 8), 512, 0, stream>>>(x, pooled);
    k_sim<<<2048, 256, 0, stream>>>(E, sl, pooled, simkey);
    k_b2<<<8, 64, 0, stream>>>(E, simkey, max_sim, norm_e, ebest);
    k_mega<<<1024, 512, 0, stream>>>(x, Wp, bprime, W2b, b2, ebest, max_sim, norm_e, out);
}

// Round 2
// 667.834 us; speedup vs baseline: 1.0419x; 1.0419x over previous
//
#include <hip/hip_runtime.h>
#include <math.h>

// ---------------- workspace layout (bytes) ----------------
#define OFF_SIMKEY   0          // u64[8]
#define OFF_POOLED   1024       // f32[8*512]
#define ZEROED_BYTES 17408
#define OFF_MAXSIM   17408      // f32[8]
#define OFF_NORME    17664      // f32[8]
#define OFF_EBEST    17920      // f32[8*512]
#define OFF_BPRIME   34304      // f32[512]
#define OFF_WP       36864      // bf16[512*512]  (W' = W1 @ Wc)
#define OFF_W2B      561152     // bf16[512*512]

typedef __attribute__((ext_vector_type(8))) short bf16x8;
typedef __attribute__((ext_vector_type(4))) float f32x4;

__device__ inline unsigned short f2bf(float f) {
    unsigned int u = __float_as_uint(f);
    unsigned int r = (u + 0x7FFFu + ((u >> 16) & 1u)) >> 16;
    return (unsigned short)r;
}

// ---------------- W' = W1 @ Wc (bf16), b' = b1 + W1 @ bc ----------------
__global__ void __launch_bounds__(256) k_pre(const float* __restrict__ W1, const float* __restrict__ Wc,
                      const float* __restrict__ b1, const float* __restrict__ bc,
                      unsigned short* __restrict__ Wp, float* __restrict__ bprime) {
    __shared__ float w1row[512];
    __shared__ float wsum[4];
    int t = threadIdx.x;
    int n = blockIdx.x >> 1, half = blockIdx.x & 1;
    if (t < 128) ((float4*)w1row)[t] = ((const float4*)(W1 + (size_t)n * 512))[t];
    __syncthreads();
    int k = half * 256 + t;
    float acc = 0.f;
#pragma unroll 8
    for (int j = 0; j < 512; ++j) acc += w1row[j] * Wc[(size_t)j * 512 + k];
    Wp[(size_t)n * 512 + k] = f2bf(acc);
    if (half == 0) {
        float p = w1row[t] * bc[t] + w1row[t + 256] * bc[t + 256];
#pragma unroll
        for (int m = 32; m >= 1; m >>= 1) p += __shfl_xor(p, m);
        if ((t & 63) == 0) wsum[t >> 6] = p;
        __syncthreads();
        if (t == 0) bprime[n] = b1[n] + wsum[0] + wsum[1] + wsum[2] + wsum[3];
    }
}

// ---------------- W2 -> bf16 ----------------
__global__ void __launch_bounds__(256) k_cast(const float* __restrict__ W2, unsigned short* __restrict__ W2b) {
    int i = blockIdx.x * 1024 + threadIdx.x * 4;
    float4 v = *(const float4*)(W2 + i);
    ushort4 o;
    o.x = f2bf(v.x); o.y = f2bf(v.y); o.z = f2bf(v.z); o.w = f2bf(v.w);
    *(ushort4*)(W2b + i) = o;
}

// ---------------- pooled sum over L (float4 loads, LDS pre-reduce) ----------------
__global__ void __launch_bounds__(512) k_pool(const float* __restrict__ x, float* __restrict__ pooled) {
    __shared__ float4 pb[4][128];
    int t = threadIdx.x;
    int q = t & 127;
    int rg = t >> 7;
    int b = blockIdx.y;
    int l0 = blockIdx.x * 128;
    const float4* p = (const float4*)(x + ((size_t)b * 8192 + l0 + rg) * 512) + q;
    float4 s = make_float4(0.f, 0.f, 0.f, 0.f);
#pragma unroll 8
    for (int i = 0; i < 32; ++i) {
        float4 v = p[(size_t)i * 512];
        s.x += v.x; s.y += v.y; s.z += v.z; s.w += v.w;
    }
    pb[rg][q] = s;
    __syncthreads();
    if (rg == 0) {
        float4 a = pb[0][q], b1_ = pb[1][q], c = pb[2][q], d = pb[3][q];
        atomicAdd(&pooled[b * 512 + q * 4 + 0], a.x + b1_.x + c.x + d.x);
        atomicAdd(&pooled[b * 512 + q * 4 + 1], a.y + b1_.y + c.y + d.y);
        atomicAdd(&pooled[b * 512 + q * 4 + 2], a.z + b1_.z + c.z + d.z);
        atomicAdd(&pooled[b * 512 + q * 4 + 3], a.w + b1_.w + c.w + d.w);
    }
}

// ---------------- sim scan: argmax cos(pooled_b, E_s) over active s ----------------
__global__ void __launch_bounds__(256) k_sim(const float* __restrict__ E, const float* __restrict__ sl,
                     const float* __restrict__ pooledws, unsigned long long* __restrict__ simkey) {
    __shared__ float ps[4096];
    __shared__ unsigned long long wkey[4][8];
    int t = threadIdx.x, lane = t & 63, w = t >> 6;
#pragma unroll
    for (int c = 0; c < 16; ++c) ps[t + c * 256] = pooledws[t + c * 256] * (1.0f / 8192.0f);
    __syncthreads();
    float pr[8][8];
#pragma unroll
    for (int b = 0; b < 8; ++b) {
        float4 v0 = *(const float4*)&ps[b * 512 + lane * 8];
        float4 v1 = *(const float4*)&ps[b * 512 + lane * 8 + 4];
        pr[b][0] = v0.x; pr[b][1] = v0.y; pr[b][2] = v0.z; pr[b][3] = v0.w;
        pr[b][4] = v1.x; pr[b][5] = v1.y; pr[b][6] = v1.z; pr[b][7] = v1.w;
    }
    float npinv[8];
#pragma unroll
    for (int b = 0; b < 8; ++b) {
        float s = 0.f;
#pragma unroll
        for (int j = 0; j < 8; ++j) s += pr[b][j] * pr[b][j];
#pragma unroll
        for (int m = 32; m >= 1; m >>= 1) s += __shfl_xor(s, m);
        npinv[b] = 1.0f / fmaxf(sqrtf(s), 1e-8f);
    }
    unsigned long long best[8];
#pragma unroll
    for (int b = 0; b < 8; ++b) best[b] = 0ull;
    int sbase = blockIdx.x * 64 + w * 16;
    float mysl = (lane < 16) ? sl[sbase + lane] : 0.f;
    unsigned long long mask = __ballot(mysl > 0.0f);
    for (int it = 0; it < 16; ++it) {
        if (!((mask >> it) & 1ull)) continue;
        int s = sbase + it;
        const float4* ep = (const float4*)(E + (size_t)s * 512);
        float4 e0 = ep[lane * 2], e1 = ep[lane * 2 + 1];
        float nrm = e0.x * e0.x + e0.y * e0.y + e0.z * e0.z + e0.w * e0.w
                  + e1.x * e1.x + e1.y * e1.y + e1.z * e1.z + e1.w * e1.w;
        float dt[8];
#pragma unroll
        for (int b = 0; b < 8; ++b)
            dt[b] = e0.x * pr[b][0] + e0.y * pr[b][1] + e0.z * pr[b][2] + e0.w * pr[b][3]
                  + e1.x * pr[b][4] + e1.y * pr[b][5] + e1.z * pr[b][6] + e1.w * pr[b][7];
#pragma unroll
        for (int m = 32; m >= 1; m >>= 1) {
            nrm += __shfl_xor(nrm, m);
#pragma unroll
            for (int b = 0; b < 8; ++b) dt[b] += __shfl_xor(dt[b], m);
        }
        float neinv = 1.0f / fmaxf(sqrtf(nrm), 1e-8f);
#pragma unroll
        for (int b = 0; b < 8; ++b) {
            float sim = dt[b] * npinv[b] * neinv;
            unsigned int u = __float_as_uint(sim);
            unsigned int k32 = (u & 0x80000000u) ? ~u : (u | 0x80000000u);
            unsigned long long key = ((unsigned long long)k32 << 32) | (unsigned int)(~(unsigned int)s);
            if (key > best[b]) best[b] = key;
        }
    }
    if (lane == 0) {
#pragma unroll
        for (int b = 0; b < 8; ++b) wkey[w][b] = best[b];
    }
    __syncthreads();
    if (t < 8) {
        unsigned long long k = wkey[0][t];
#pragma unroll
        for (int w2 = 1; w2 < 4; ++w2) if (wkey[w2][t] > k) k = wkey[w2][t];
        if (k) atomicMax(&simkey[t], k);
    }
}

// ---------------- decode best, gather embedding + norm ----------------
__global__ void __launch_bounds__(64) k_b2(const float* __restrict__ E, const unsigned long long* __restrict__ simkey,
                    float* __restrict__ max_sim, float* __restrict__ norm_e, float* __restrict__ ebest) {
    int b = blockIdx.x, lane = threadIdx.x;
    unsigned long long key = simkey[b];
    float ms; unsigned int idx;
    if (key == 0ull) { ms = -1e30f; idx = 0u; }
    else {
        unsigned int k32 = (unsigned int)(key >> 32);
        unsigned int u = (k32 & 0x80000000u) ? (k32 & 0x7FFFFFFFu) : ~k32;
        ms = __uint_as_float(u);
        idx = ~(unsigned int)(key & 0xFFFFFFFFull);
    }
    const float4* ep = (const float4*)(E + (size_t)idx * 512);
    float4 e0 = ep[lane * 2], e1 = ep[lane * 2 + 1];
    *(float4*)&ebest[b * 512 + lane * 8] = e0;
    *(float4*)&ebest[b * 512 + lane * 8 + 4] = e1;
    float s = e0.x * e0.x + e0.y * e0.y + e0.z * e0.z + e0.w * e0.w
            + e1.x * e1.x + e1.y * e1.y + e1.z * e1.z + e1.w * e1.w;
#pragma unroll
    for (int m = 32; m >= 1; m >>= 1) s += __shfl_xor(s, m);
    if (lane == 0) { max_sim[b] = ms; norm_e[b] = fmaxf(sqrtf(s), 1e-8f); }
}

// ---------------- mega v4: 2 blocks/CU (Hs aliases Ts) + reg-pipelined B ----------------
// v3 post-mortem: direct-L2 B put a ~200cy load on the MFMA path with no pipelining,
// at 1 block/CU (LDS 137KB). Fixes:
//  (a) Hs overlays Ts (Ts dead after GEMM1 K-loop) -> LDS 71680 B -> 2 blocks/CU,
//      4 waves/SIMD. __launch_bounds__(512,4) caps VGPR at 128 to keep it.
//  (b) B fragments double-buffered in registers: issue kt+1's 4 dwordx4 L2 loads
//      before kt's 16 MFMAs; full unroll SSA-renames the copies.
// A keeps its 8x LDS broadcast (all 16 k-chunks staged once in prologue).
// LDS: Ts/Hs 64K @0 | red 6K @65536 = 71680.
__global__ void __launch_bounds__(512, 4) k_mega(
        const float* __restrict__ x, const unsigned short* __restrict__ Wp,
        const float* __restrict__ bprime, const unsigned short* __restrict__ W2b,
        const float* __restrict__ b2, const float* __restrict__ ebest,
        const float* __restrict__ max_sim, const float* __restrict__ norm_e,
        float* __restrict__ out) {
    __shared__ char smem[71680];
    unsigned int*   Ts32 = (unsigned int*)(smem);
    unsigned short* Ts   = (unsigned short*)(smem);
    unsigned short* Hs   = (unsigned short*)(smem);          // aliases Ts (Ts dead after GEMM1)
    float*          red  = (float*)(smem + 65536);

    const int t = threadIdx.x;
    const int lane = t & 63, w = t >> 6;
    const int l15 = lane & 15, quad = lane >> 4;
    const int gr0 = blockIdx.x * 64;
    const int b = gr0 >> 13;

    // ---- A staging geometry: thread owns row r, dword pair {cc, cc+8} per kt ----
    const int r = t >> 3, cc = t & 7;
    const int sR = (r >> 1) & 3;
    const int d0 = (((cc >> 2) ^ sR) << 2) | (cc & 3);
    const int d1 = ((((cc >> 2) + 2) ^ sR) << 2) | (cc & 3);

    // fragment read offsets (ushort units, swizzled)
    int tsoff[4], hoff[4];
#pragma unroll
    for (int i = 0; i < 4; ++i) {
        int rowA = i * 16 + l15;
        tsoff[i] = rowA * 32 + ((quad ^ ((rowA >> 1) & 3)) << 3);
        hoff[i]  = rowA * 32 + ((quad ^ ((rowA >> 2) & 3)) << 3);
    }

    // B fragment pointers: direct global (L2-hit), dwordx4 per frag, kt*32 folds to imm offset
    const unsigned short* bp1[4];
    const unsigned short* bp2[4];
#pragma unroll
    for (int j = 0; j < 4; ++j) {
        int n = w * 64 + j * 16 + l15;
        bp1[j] = Wp  + n * 512 + quad * 8;
        bp2[j] = W2b + n * 512 + quad * 8;
    }

    // ---- prologue: stage ALL 16 A k-chunks into Ts (bf16, swizzled) ----
    {
        int gr = gr0 + r;
        bool z = ((gr & 8191) == 0);
        const float* src = x + ((size_t)gr - 1) * 512 + cc * 2;
#pragma unroll
        for (int kt = 0; kt < 16; ++kt) {
            float2 v0 = make_float2(0.f, 0.f), v1 = make_float2(0.f, 0.f);
            if (!z) { v0 = *(const float2*)(src + kt * 32); v1 = *(const float2*)(src + kt * 32 + 16); }
            Ts32[kt * 1024 + r * 16 + d0] = (unsigned int)f2bf(v0.x) | ((unsigned int)f2bf(v0.y) << 16);
            Ts32[kt * 1024 + r * 16 + d1] = (unsigned int)f2bf(v1.x) | ((unsigned int)f2bf(v1.y) << 16);
        }
    }
    __syncthreads();

    // ================= GEMM1 K-loop (barrier-free, reg-pipelined B) =================
    f32x4 acc[4][4];
#pragma unroll
    for (int i = 0; i < 4; ++i)
#pragma unroll
        for (int j = 0; j < 4; ++j) acc[i][j] = (f32x4){0.f, 0.f, 0.f, 0.f};
    {
        bf16x8 bcur[4], bnxt[4];
#pragma unroll
        for (int j = 0; j < 4; ++j) bcur[j] = *(const bf16x8*)(bp1[j]);
#pragma unroll
        for (int kt = 0; kt < 16; ++kt) {
            if (kt < 15) {
#pragma unroll
                for (int j = 0; j < 4; ++j) bnxt[j] = *(const bf16x8*)(bp1[j] + (kt + 1) * 32);
            }
            bf16x8 af[4];
#pragma unroll
            for (int i = 0; i < 4; ++i) af[i] = *(const bf16x8*)&Ts[kt * 2048 + tsoff[i]];
#pragma unroll
            for (int i = 0; i < 4; ++i)
#pragma unroll
                for (int j = 0; j < 4; ++j)
                    acc[i][j] = __builtin_amdgcn_mfma_f32_16x16x32_bf16(af[i], bcur[j], acc[i][j], 0, 0, 0);
#pragma unroll
            for (int j = 0; j < 4; ++j) bcur[j] = bnxt[j];
        }
    }
    __syncthreads();   // all waves done reading Ts before Hs overwrites it

    // ---- GEMM1 epilogue: bias + exact gelu -> Hs (swizzled, aliases Ts) ----
    {
        float bpj[4];
#pragma unroll
        for (int j = 0; j < 4; ++j) bpj[j] = bprime[w * 64 + j * 16 + l15];
#pragma unroll
        for (int i = 0; i < 4; ++i)
#pragma unroll
            for (int j = 0; j < 4; ++j)
#pragma unroll
                for (int rg = 0; rg < 4; ++rg) {
                    int m = i * 16 + quad * 4 + rg;
                    int ktc = w * 2 + (j >> 1);
                    int grp = ((j & 1) * 2 + (l15 >> 3)) ^ ((m >> 2) & 3);
                    float v = acc[i][j][rg] + bpj[j];
                    v = 0.5f * v * (1.0f + erff(v * 0.70710678118f));
                    Hs[ktc * 2048 + m * 32 + grp * 8 + (l15 & 7)] = f2bf(v);
                }
    }
    __syncthreads();

    // ================= GEMM2 K-loop (barrier-free, reg-pipelined B) =================
    f32x4 acc2[4][4];
#pragma unroll
    for (int i = 0; i < 4; ++i)
#pragma unroll
        for (int j = 0; j < 4; ++j) acc2[i][j] = (f32x4){0.f, 0.f, 0.f, 0.f};
    {
        bf16x8 bcur[4], bnxt[4];
#pragma unroll
        for (int j = 0; j < 4; ++j) bcur[j] = *(const bf16x8*)(bp2[j]);
#pragma unroll
        for (int kt = 0; kt < 16; ++kt) {
            if (kt < 15) {
#pragma unroll
                for (int j = 0; j < 4; ++j) bnxt[j] = *(const bf16x8*)(bp2[j] + (kt + 1) * 32);
            }
            bf16x8 af[4];
#pragma unroll
            for (int i = 0; i < 4; ++i) af[i] = *(const bf16x8*)&Hs[kt * 2048 + hoff[i]];
#pragma unroll
            for (int i = 0; i < 4; ++i)
#pragma unroll
                for (int j = 0; j < 4; ++j)
                    acc2[i][j] = __builtin_amdgcn_mfma_f32_16x16x32_bf16(af[i], bcur[j], acc2[i][j], 0, 0, 0);
#pragma unroll
            for (int j = 0; j < 4; ++j) bcur[j] = bnxt[j];
        }
    }

    // ---- GEMM2 epilogue: ssd/nx2/xdot partials, cross-wave reduce, out ----
    {
        float b2j[4], ej[4];
#pragma unroll
        for (int j = 0; j < 4; ++j) {
            int n = w * 64 + j * 16 + l15;
            b2j[j] = b2[n];
            ej[j] = ebest[b * 512 + n];
        }
#pragma unroll
        for (int i = 0; i < 4; ++i)
#pragma unroll
            for (int rg = 0; rg < 4; ++rg) {
                int m = i * 16 + quad * 4 + rg;
                int gr = gr0 + m;
                float sd = 0.f, sx = 0.f, sdt = 0.f;
#pragma unroll
                for (int j = 0; j < 4; ++j) {
                    int n = w * 64 + j * 16 + l15;
                    float p = acc2[i][j][rg] + b2j[j];
                    float xv = x[(size_t)gr * 512 + n];
                    float d = xv - p;
                    sd += d * d; sx += xv * xv; sdt += xv * ej[j];
                }
#pragma unroll
                for (int mm = 8; mm >= 1; mm >>= 1) {
                    sd += __shfl_xor(sd, mm);
                    sx += __shfl_xor(sx, mm);
                    sdt += __shfl_xor(sdt, mm);
                }
                if (l15 == 0) {
                    red[(m * 8 + w) * 3 + 0] = sd;
                    red[(m * 8 + w) * 3 + 1] = sx;
                    red[(m * 8 + w) * 3 + 2] = sdt;
                }
            }
    }
    __syncthreads();
    if (t < 64) {
        float sd = 0.f, sx = 0.f, sdt = 0.f;
#pragma unroll
        for (int w2 = 0; w2 < 8; ++w2) {
            sd  += red[(t * 8 + w2) * 3 + 0];
            sx  += red[(t * 8 + w2) * 3 + 1];
            sdt += red[(t * 8 + w2) * 3 + 2];
        }
        float ps = sqrtf(sd * (1.0f / 512.0f));
        float ms = max_sim[b];
        float c = 0.f;
        if (ms > 0.3f) {
            float nx = fmaxf(sqrtf(sx), 1e-8f);
            c = 2.0f * (1.0f - sdt / (nx * norm_e[b]));
        }
        out[gr0 + t] = fmaxf(ps, c);
    }
}

extern "C" void kernel_launch(void* const* d_in, const int* in_sizes, int n_in,
                              void* d_out, int out_size, void* d_ws, size_t ws_size,
                              hipStream_t stream) {
    const float* x  = (const float*)d_in[0];
    const float* Wc = (const float*)d_in[1];
    const float* bc = (const float*)d_in[2];
    const float* W1 = (const float*)d_in[3];
    const float* b1 = (const float*)d_in[4];
    const float* W2 = (const float*)d_in[5];
    const float* b2 = (const float*)d_in[6];
    const float* E  = (const float*)d_in[7];
    const float* sl = (const float*)d_in[8];

    char* ws = (char*)d_ws;
    unsigned long long* simkey = (unsigned long long*)(ws + OFF_SIMKEY);
    float* pooled  = (float*)(ws + OFF_POOLED);
    float* max_sim = (float*)(ws + OFF_MAXSIM);
    float* norm_e  = (float*)(ws + OFF_NORME);
    float* ebest   = (float*)(ws + OFF_EBEST);
    float* bprime  = (float*)(ws + OFF_BPRIME);
    unsigned short* Wp  = (unsigned short*)(ws + OFF_WP);
    unsigned short* W2b = (unsigned short*)(ws + OFF_W2B);
    float* out = (float*)d_out;

    hipMemsetAsync(ws, 0, ZEROED_BYTES, stream);
    k_pre<<<1024, 256, 0, stream>>>(W1, Wc, b1, bc, Wp, bprime);
    k_cast<<<256, 256, 0, stream>>>(W2, W2b);
    k_pool<<<dim3(64, 8), 512, 0, stream>>>(x, pooled);
    k_sim<<<2048, 256, 0, stream>>>(E, sl, pooled, simkey);
    k_b2<<<8, 64, 0, stream>>>(E, simkey, max_sim, norm_e, ebest);
    k_mega<<<1024, 512, 0, stream>>>(x, Wp, bprime, W2b, b2, ebest, max_sim, norm_e, out);
}